// Round 13
// baseline (233.069 us; speedup 1.0000x reference)
//
#include <hip/hip_runtime.h>

typedef float f32x4 __attribute__((ext_vector_type(4)));
typedef short short8 __attribute__((ext_vector_type(8)));
typedef short short4v __attribute__((ext_vector_type(4)));
typedef unsigned int uint2v __attribute__((ext_vector_type(2)));
typedef unsigned short ushort_t;

#define D_MODEL 1024
#define N_HEAD 16
#define SEQ 2048
#define BATCH 2
#define M_TOK 4096  // B*S
#define HD 1024     // N_HEAD*D_K
#define NT 32       // SEQ/64 k-tiles
#define APANEL 131072  // 4096*32 elements per A-side k-panel
#define WPANEL 32768   // 1024*32 elements per weight k-panel
// (1/sqrt(64)) * log2(e), folded into Q-GEMM epilogue; attention uses exp2
#define QSCALE_L2E 0.1803368801111f

__device__ __forceinline__ ushort_t f2bf(float f) {
    union { float f; unsigned int u; } x; x.f = f;
    unsigned int r = x.u + 0x7fffu + ((x.u >> 16) & 1u);
    return (ushort_t)(r >> 16);
}

__device__ __forceinline__ void async_copy16(const ushort_t* gptr, ushort_t* lptr) {
    __builtin_amdgcn_global_load_lds(
        (const __attribute__((address_space(1))) unsigned int*)gptr,
        (__attribute__((address_space(3))) unsigned int*)lptr, 16, 0, 0);
}

// ---- fused prep: z<4 weight transpose+cast -> panel layout [k/32][1024][32];
//      z>=4 q/k/v cast -> panel layout [k/32][4096][32] ----
// (round-7 lesson: in-GEMM fp32 consumption costs more than this pass saves)
__global__ __launch_bounds__(256) void prep_fused(const float* __restrict__ w0,
                                                  const float* __restrict__ w1,
                                                  const float* __restrict__ w2,
                                                  const float* __restrict__ w3,
                                                  ushort_t* __restrict__ o0,
                                                  ushort_t* __restrict__ o1,
                                                  ushort_t* __restrict__ o2,
                                                  ushort_t* __restrict__ o3,
                                                  const float* __restrict__ q,
                                                  const float* __restrict__ k,
                                                  const float* __restrict__ v,
                                                  ushort_t* __restrict__ qo,
                                                  ushort_t* __restrict__ ko,
                                                  ushort_t* __restrict__ vo) {
    const int z = blockIdx.z;
    const int tid = threadIdx.x;
    const int flat = blockIdx.x + 64 * blockIdx.y;  // 0..2047
    if (z < 4) {
        if (flat >= 1024) return;
        const int C = D_MODEL;
        const float* in = (z == 0) ? w0 : (z == 1) ? w1 : (z == 2) ? w2 : w3;
        ushort_t* out = (z == 0) ? o0 : (z == 1) ? o1 : (z == 2) ? o2 : o3;
        __shared__ ushort_t t[32][33];
        int bc = (flat & 31) * 32, br = (flat >> 5) * 32;  // br = k-block, bc = n-block
        int tx = tid & 31, ty = tid >> 5;
        for (int i = ty; i < 32; i += 8)
            t[i][tx] = f2bf(in[(size_t)(br + i) * C + bc + tx]);
        __syncthreads();
        // element (n = bc+i, k = br+tx) -> panel (br>>5), addr n*32 + tx
        size_t pbase = (size_t)(br >> 5) * WPANEL;
        for (int i = ty; i < 32; i += 8)
            out[pbase + (size_t)(bc + i) * 32 + tx] = t[tx][i];
    } else {
        const float* s = (z == 4) ? q : (z == 5) ? k : v;
        ushort_t* d = (z == 4) ? qo : (z == 5) ? ko : vo;
        size_t i = ((size_t)flat * 256 + tid) * 8;
        int m = (int)(i >> 10), k0 = (int)(i & 1023);
        float4 a = *(const float4*)(s + i);
        float4 b = *(const float4*)(s + i + 4);
        ushort_t tmp[8] = {f2bf(a.x), f2bf(a.y), f2bf(a.z), f2bf(a.w),
                           f2bf(b.x), f2bf(b.y), f2bf(b.z), f2bf(b.w)};
        *(short8*)(d + (size_t)(k0 >> 5) * APANEL + (size_t)m * 32 + (k0 & 31)) = *(short8*)tmp;
    }
}

// ---- QKV projection: 128x128 tile, BK=64 (2 panels/iter), grid.z batched ----
// ROUND-6 VERIFIED FORM (BK=32 dbuf regressed +3us in round 8 -> reverted).
// Grid (m, n, z): m on blockIdx.x so same-A blocks share an XCD L2.
// z==0: Q scaled by QSCALE_L2E. z==1: K. z==2: V -> blocked V4 layout.
__global__ __launch_bounds__(256) void gemm_qkv(const ushort_t* __restrict__ qb,
                                                const ushort_t* __restrict__ kb,
                                                const ushort_t* __restrict__ vb,
                                                const ushort_t* __restrict__ wq,
                                                const ushort_t* __restrict__ wk,
                                                const ushort_t* __restrict__ wv,
                                                ushort_t* __restrict__ Qo,
                                                ushort_t* __restrict__ Ko,
                                                ushort_t* __restrict__ V4) {
    __shared__ ushort_t As[2][128 * 32];
    __shared__ ushort_t Bs[2][128 * 32];
    const int z = blockIdx.z;
    const ushort_t* A = (z == 0) ? qb : (z == 1) ? kb : vb;
    const ushort_t* Bt = (z == 0) ? wq : (z == 1) ? wk : wv;
    const int tid = threadIdx.x;
    const int wave = tid >> 6, lane = tid & 63;
    const int quad = lane >> 4, l16 = lane & 15;
    const int m0 = blockIdx.x * 128, n0 = blockIdx.y * 128;
    const int wm = (wave >> 1) * 64, wn = (wave & 1) * 64;
    const int N = D_MODEL;

    f32x4 acc[4][4];
    for (int i = 0; i < 4; ++i)
        for (int j = 0; j < 4; ++j) acc[i][j] = (f32x4){0.f, 0.f, 0.f, 0.f};

    for (int it = 0; it < 16; ++it) {
        __syncthreads();
        const ushort_t* Ap = A + (size_t)(it * 2) * APANEL + (size_t)m0 * 32;
        const ushort_t* Bp = Bt + (size_t)(it * 2) * WPANEL + (size_t)n0 * 32;
        #pragma unroll
        for (int hf = 0; hf < 2; ++hf) {
            #pragma unroll
            for (int c = 0; c < 2; ++c) {
                int off = (wave * 2 + c) * 512;
                async_copy16(Ap + hf * APANEL + off + lane * 8, &As[hf][off] + lane * 8);
                async_copy16(Bp + hf * WPANEL + off + lane * 8, &Bs[hf][off] + lane * 8);
            }
        }
        __syncthreads();
        short8 af[4][2], bfr[4][2];
        #pragma unroll
        for (int i = 0; i < 4; ++i)
            #pragma unroll
            for (int sk = 0; sk < 2; ++sk)
                af[i][sk] = *(const short8*)&As[sk][(wm + i * 16 + l16) * 32 + quad * 8];
        #pragma unroll
        for (int j = 0; j < 4; ++j)
            #pragma unroll
            for (int sk = 0; sk < 2; ++sk)
                bfr[j][sk] = *(const short8*)&Bs[sk][(wn + j * 16 + l16) * 32 + quad * 8];
        #pragma unroll
        for (int sk = 0; sk < 2; ++sk)
            #pragma unroll
            for (int i = 0; i < 4; ++i)
                #pragma unroll
                for (int j = 0; j < 4; ++j)
                    acc[i][j] = __builtin_amdgcn_mfma_f32_16x16x32_bf16(af[i][sk], bfr[j][sk], acc[i][j], 0, 0, 0);
    }
    if (z == 2) {
        // V4 blocked layout: tile64 = 64-token group; w-subtile = i; token slot rotated
        const int tile64 = m0 + wm;
        const int b2 = tile64 >> 11;            // /SEQ
        const int kt = (tile64 & 2047) >> 6;
        #pragma unroll
        for (int i = 0; i < 4; ++i)
            #pragma unroll
            for (int j = 0; j < 4; ++j) {
                int n = n0 + wn + j * 16 + l16;
                int h2 = n >> 6, d = n & 63;
                int quadR = (quad + ((n >> 2) & 3)) & 3;
                ushort_t tmp[4];
                #pragma unroll
                for (int r = 0; r < 4; ++r) tmp[r] = f2bf(acc[i][j][r]);
                size_t dst = ((((size_t)(h2 * 2 + b2) * NT + kt) * 4 + i) << 10) + d * 16 + quadR * 4;
                *(short4v*)&V4[dst] = *(short4v*)tmp;
            }
    } else {
        ushort_t* C = (z == 0) ? Qo : Ko;
        const float scale = (z == 0) ? QSCALE_L2E : 1.0f;
        #pragma unroll
        for (int i = 0; i < 4; ++i)
            #pragma unroll
            for (int j = 0; j < 4; ++j) {
                int n = n0 + wn + j * 16 + l16;
                #pragma unroll
                for (int r = 0; r < 4; ++r) {
                    int m = m0 + wm + i * 16 + quad * 4 + r;
                    C[(size_t)m * N + n] = f2bf(acc[i][j][r] * scale);
                }
            }
    }
}

// ---- FC projection: 128x64 tiles, BK=64 panels, fused bias + residual, fp32 out ----
// ROUND-6 VERIFIED FORM. Grid (m, n): m on blockIdx.x for XCD L2 locality.
__global__ __launch_bounds__(256) void gemm_fc(const ushort_t* __restrict__ A,
                                               const ushort_t* __restrict__ Bt,
                                               float* __restrict__ Cf,
                                               const float* __restrict__ bias,
                                               const float* __restrict__ resid) {
    __shared__ ushort_t As[2][128 * 32];
    __shared__ ushort_t Bs[2][64 * 32];
    const int tid = threadIdx.x;
    const int wave = tid >> 6, lane = tid & 63;
    const int quad = lane >> 4, l16 = lane & 15;
    const int m0 = blockIdx.x * 128, n0 = blockIdx.y * 64;
    const int N = D_MODEL;

    f32x4 acc[2][4];
    for (int i = 0; i < 2; ++i)
        for (int j = 0; j < 4; ++j) acc[i][j] = (f32x4){0.f, 0.f, 0.f, 0.f};

    for (int it = 0; it < 16; ++it) {
        __syncthreads();
        const ushort_t* Ap = A + (size_t)(it * 2) * APANEL + (size_t)m0 * 32;
        const ushort_t* Bp = Bt + (size_t)(it * 2) * WPANEL + (size_t)n0 * 32;
        #pragma unroll
        for (int c = 0; c < 4; ++c) {  // A: 16 instrs, wave does 4
            int g = wave * 4 + c;
            int sk = g >> 3, off = (g & 7) * 512;
            async_copy16(Ap + sk * APANEL + off + lane * 8, &As[sk][off] + lane * 8);
        }
        #pragma unroll
        for (int c = 0; c < 2; ++c) {  // B: 8 instrs, wave does 2
            int g = wave * 2 + c;
            int sk = g >> 2, off = (g & 3) * 512;
            async_copy16(Bp + sk * WPANEL + off + lane * 8, &Bs[sk][off] + lane * 8);
        }
        __syncthreads();
        short8 af[2][2], bfr[4][2];
        #pragma unroll
        for (int i = 0; i < 2; ++i)
            #pragma unroll
            for (int sk = 0; sk < 2; ++sk)
                af[i][sk] = *(const short8*)&As[sk][(wave * 32 + i * 16 + l16) * 32 + quad * 8];
        #pragma unroll
        for (int j = 0; j < 4; ++j)
            #pragma unroll
            for (int sk = 0; sk < 2; ++sk)
                bfr[j][sk] = *(const short8*)&Bs[sk][(j * 16 + l16) * 32 + quad * 8];
        #pragma unroll
        for (int sk = 0; sk < 2; ++sk)
            #pragma unroll
            for (int i = 0; i < 2; ++i)
                #pragma unroll
                for (int j = 0; j < 4; ++j)
                    acc[i][j] = __builtin_amdgcn_mfma_f32_16x16x32_bf16(af[i][sk], bfr[j][sk], acc[i][j], 0, 0, 0);
    }
    #pragma unroll
    for (int i = 0; i < 2; ++i)
        #pragma unroll
        for (int j = 0; j < 4; ++j) {
            int n = n0 + j * 16 + l16;
            #pragma unroll
            for (int r = 0; r < 4; ++r) {
                int m = m0 + wave * 32 + i * 16 + quad * 4 + r;
                Cf[(size_t)m * N + n] = acc[i][j][r] + bias[n] + resid[(size_t)m * N + n];
            }
        }
}

// ---- flash attention: parity-unrolled (x2) K/V pipeline ----
// ROUND-9/11 VERIFIED KERNEL (session best: 55.7-56.5us, MfmaUtil 35%). Ledger:
//  - VALU trim (cvt_pk): counters moved, time flat -> latency-bound, not issue-bound.
//  - k-split x2 (cross-block combine): NaN twice -> abandoned.
//  - q-split x2: occupancy 21->49% but 112us -> occupancy NOT binding.
//  - parity kfA/kfB (no end-of-iter copy): removed forced per-iter vmcnt drain,
//    67->55.7us. K/V flight window >= 1.5 iterations.
//  - carried-PV (round 10): spilled (WRITE 9.2->22.4MB), 77.5us -> reverted.
//  - setprio T5 (round 12): +2us regression (both pipes ~35% -> symmetric
//    pressure; prio starves prefetch issue) -> reverted.
__global__ __launch_bounds__(256, 3) void attn64(const ushort_t* __restrict__ Qh,
                                                 const ushort_t* __restrict__ Kh,
                                                 const ushort_t* __restrict__ V4,
                                                 ushort_t* __restrict__ O) {
    // loop: V buffers 4 waves x 3 bufs x 2KB = 24576 B; epilogue overlay 64x66 fp32 + lsb
    __shared__ __align__(16) char smem[25600];
    const int tid = threadIdx.x;
    const int wave = tid >> 6, lane = tid & 63;
    const int quad = lane >> 4, l16 = lane & 15;
    const int h = blockIdx.x, b = blockIdx.y, qt = blockIdx.z;
    const size_t base = (size_t)b * SEQ * HD + h * 64;
    const ushort_t* Qb = Qh + base + (size_t)(qt * 64) * HD;
    const ushort_t* Kb = Kh + base;
    // wave's V stream: V4[h][b][kt][wave][1024], kt stride 4096 el
    const ushort_t* Vg = V4 + (((size_t)(h * 2 + b) * NT * 4) + wave) * 1024 + lane * 8;

    ushort_t* Vw = (ushort_t*)smem + wave * 3072;
    float* lsb = (float*)(smem + 24576);

    short8 qf[4][2];
    #pragma unroll
    for (int nt = 0; nt < 4; ++nt)
        #pragma unroll
        for (int s = 0; s < 2; ++s)
            qf[nt][s] = *(const short8*)(Qb + (size_t)(nt * 16 + l16) * HD + s * 32 + quad * 8);

    f32x4 oacc[4][4];
    #pragma unroll
    for (int nt = 0; nt < 4; ++nt)
        #pragma unroll
        for (int dt = 0; dt < 4; ++dt) oacc[nt][dt] = (f32x4){0.f, 0.f, 0.f, 0.f};
    float lsum[4] = {0.f, 0.f, 0.f, 0.f};

    const ushort_t* Kr = Kb + (size_t)(wave * 16 + l16) * HD + quad * 8;
    ushort_t* VLd = Vw + lane * 8;

    // prologue issue order: qf(8) [above], K0->kfA(2), V0(2), K1->kfB(2), V1(2)
    short8 kfA[2], kfB[2];
    #pragma unroll
    for (int s = 0; s < 2; ++s) kfA[s] = *(const short8*)(Kr + s * 32);
    #pragma unroll
    for (int c = 0; c < 2; ++c) async_copy16(Vg + c * 512, VLd + c * 512);
    #pragma unroll
    for (int s = 0; s < 2; ++s) kfB[s] = *(const short8*)(Kr + (size_t)64 * HD + s * 32);
    #pragma unroll
    for (int c = 0; c < 2; ++c) async_copy16(Vg + 4096 + c * 512, VLd + 1024 + c * 512);

    ushort_t *s0 = Vw, *s1 = Vw + 1024, *s2 = Vw + 2048;
    const int rot = (l16 >> 2) & 3;

// one kt step. KF = kfA/kfB by parity (no copies). After the S-MFMAs consume
// KF, reload it with K(KT+2) (WAR-clean) and issue V(KT+2) DMA into SPF.
#define ATTN_STEP(KT, KF, SUSE, SPF, WAITIMM, DO_PF)                                         \
    {                                                                                        \
        __builtin_amdgcn_s_waitcnt(WAITIMM);                                                 \
        short4v vf[4];                                                                       \
        _Pragma("unroll")                                                                    \
        for (int dt = 0; dt < 4; ++dt)                                                       \
            vf[dt] = *(const short4v*)&(SUSE)[(dt * 16 + l16) * 16 + (((quad + rot) & 3) * 4)]; \
        f32x4 sacc[4];                                                                       \
        _Pragma("unroll")                                                                    \
        for (int nt = 0; nt < 4; ++nt) sacc[nt] = (f32x4){0.f, 0.f, 0.f, 0.f};               \
        _Pragma("unroll")                                                                    \
        for (int s = 0; s < 2; ++s)                                                          \
            _Pragma("unroll")                                                                \
            for (int nt = 0; nt < 4; ++nt)                                                   \
                sacc[nt] = __builtin_amdgcn_mfma_f32_16x16x32_bf16(KF[s], qf[nt][s],         \
                                                                   sacc[nt], 0, 0, 0);       \
        if (DO_PF) {                                                                         \
            _Pragma("unroll")                                                                \
            for (int s = 0; s < 2; ++s)                                                      \
                KF[s] = *(const short8*)(Kr + (size_t)((KT) + 2) * 64 * HD + s * 32);        \
            _Pragma("unroll")                                                                \
            for (int c = 0; c < 2; ++c)                                                      \
                async_copy16(Vg + (size_t)((KT) + 2) * 4096 + c * 512,                       \
                             (SPF) + lane * 8 + c * 512);                                    \
        }                                                                                    \
        short4v pf[4];                                                                       \
        _Pragma("unroll")                                                                    \
        for (int nt = 0; nt < 4; ++nt) {                                                     \
            float p0 = __builtin_amdgcn_exp2f(sacc[nt][0]);                                  \
            float p1 = __builtin_amdgcn_exp2f(sacc[nt][1]);                                  \
            float p2 = __builtin_amdgcn_exp2f(sacc[nt][2]);                                  \
            float p3 = __builtin_amdgcn_exp2f(sacc[nt][3]);                                  \
            lsum[nt] += (p0 + p1) + (p2 + p3);                                               \
            unsigned int lo, hi;                                                             \
            asm("v_cvt_pk_bf16_f32 %0, %1, %2" : "=v"(lo) : "v"(p0), "v"(p1));               \
            asm("v_cvt_pk_bf16_f32 %0, %1, %2" : "=v"(hi) : "v"(p2), "v"(p3));               \
            uint2v pk;                                                                       \
            pk.x = lo;                                                                       \
            pk.y = hi;                                                                       \
            pf[nt] = __builtin_bit_cast(short4v, pk);                                        \
        }                                                                                    \
        _Pragma("unroll")                                                                    \
        for (int nt = 0; nt < 4; ++nt)                                                       \
            _Pragma("unroll")                                                                \
            for (int dt = 0; dt < 4; ++dt)                                                   \
                oacc[nt][dt] = __builtin_amdgcn_mfma_f32_16x16x16bf16_1k(pf[nt], vf[dt],     \
                                                                         oacc[nt][dt],       \
                                                                         0, 0, 0);           \
    }

    for (int kt0 = 0; kt0 < 30; kt0 += 2) {
        ATTN_STEP(kt0,     kfA, s0, s2, 0x0F74, true);   // vmcnt(4)
        ATTN_STEP(kt0 + 1, kfB, s1, s0, 0x0F74, true);   // vmcnt(4)
        // ring rotate by 2: next body's (s0,s1,s2) = (old s2, old s0, old s1)
        ushort_t* t = s0; s0 = s2; s2 = s1; s1 = t;
    }
    ATTN_STEP(30, kfA, s0, s2, 0x0F74, false);           // vmcnt(4)
    ATTN_STEP(31, kfB, s1, s0, 0x0F70, false);           // vmcnt(0)
#undef ATTN_STEP

    #pragma unroll
    for (int nt = 0; nt < 4; ++nt) {
        lsum[nt] += __shfl_xor(lsum[nt], 16, 64);
        lsum[nt] += __shfl_xor(lsum[nt], 32, 64);
    }
    if (quad == 0) {
        #pragma unroll
        for (int nt = 0; nt < 4; ++nt) lsb[wave * 64 + nt * 16 + l16] = lsum[nt];
    }
    __syncthreads();

    float* R = (float*)smem;  // 64x66 fp32
    #pragma unroll
    for (int w = 0; w < 4; ++w) {
        if (wave == w) {
            #pragma unroll
            for (int nt = 0; nt < 4; ++nt)
                #pragma unroll
                for (int dt = 0; dt < 4; ++dt)
                    #pragma unroll
                    for (int i = 0; i < 4; ++i) {
                        int idx = (nt * 16 + quad * 4 + i) * 66 + dt * 16 + l16;
                        if (w == 0) R[idx] = oacc[nt][dt][i];
                        else        R[idx] += oacc[nt][dt][i];
                    }
        }
        __syncthreads();
    }
    float inv[4];
    #pragma unroll
    for (int i = 0; i < 4; ++i) {
        int qrow = wave * 16 + quad * 4 + i;
        float t = lsb[qrow] + lsb[64 + qrow] + lsb[128 + qrow] + lsb[192 + qrow];
        inv[i] = 1.f / t;
    }
    // O in panel layout: k = h*64 + dt*16 + l16 -> panel h*2 + (dt>>1)
    #pragma unroll
    for (int i = 0; i < 4; ++i) {
        int qrow = wave * 16 + quad * 4 + i;
        size_t tok = (size_t)b * SEQ + qt * 64 + qrow;
        #pragma unroll
        for (int dt = 0; dt < 4; ++dt) {
            int d = dt * 16 + l16;
            size_t dst = (size_t)(h * 2 + (dt >> 1)) * APANEL + tok * 32 + (dt & 1) * 16 + l16;
            O[dst] = f2bf(R[qrow * 66 + d] * inv[i]);
        }
    }
}

// ---------------- in-place LayerNorm, one block per row ----------------
__global__ __launch_bounds__(256) void ln_kernel(float* __restrict__ x,
                                                 const float* __restrict__ gamma,
                                                 const float* __restrict__ beta) {
    const int D = D_MODEL;
    float* xr = x + (size_t)blockIdx.x * D;
    const int tid = threadIdx.x;
    float4 v = *(const float4*)(xr + tid * 4);
    float s = v.x + v.y + v.z + v.w;
    float s2 = v.x * v.x + v.y * v.y + v.z * v.z + v.w * v.w;
    #pragma unroll
    for (int off = 1; off < 64; off <<= 1) {
        s += __shfl_xor(s, off, 64);
        s2 += __shfl_xor(s2, off, 64);
    }
    __shared__ float ws1[4], ws2[4];
    int wave = tid >> 6, lane = tid & 63;
    if (lane == 0) { ws1[wave] = s; ws2[wave] = s2; }
    __syncthreads();
    s = ws1[0] + ws1[1] + ws1[2] + ws1[3];
    s2 = ws2[0] + ws2[1] + ws2[2] + ws2[3];
    float mean = s * (1.f / D);
    float var = s2 * (1.f / D) - mean * mean;
    float rstd = rsqrtf(var + 1e-6f);
    float4 g = *(const float4*)(gamma + tid * 4);
    float4 bt = *(const float4*)(beta + tid * 4);
    float4 o;
    o.x = (v.x - mean) * rstd * g.x + bt.x;
    o.y = (v.y - mean) * rstd * g.y + bt.y;
    o.z = (v.z - mean) * rstd * g.z + bt.z;
    o.w = (v.w - mean) * rstd * g.w + bt.w;
    *(float4*)(xr + tid * 4) = o;
}

extern "C" void kernel_launch(void* const* d_in, const int* in_sizes, int n_in,
                              void* d_out, int out_size, void* d_ws, size_t ws_size,
                              hipStream_t stream) {
    const float* q = (const float*)d_in[0];
    const float* k = (const float*)d_in[1];
    const float* v = (const float*)d_in[2];
    const float* Wq = (const float*)d_in[3];
    const float* Wk = (const float*)d_in[4];
    const float* Wv = (const float*)d_in[5];
    const float* Wfc = (const float*)d_in[6];
    const float* bfc = (const float*)d_in[7];
    const float* gamma = (const float*)d_in[8];
    const float* beta = (const float*)d_in[9];
    float* out = (float*)d_out;

    char* ws = (char*)d_ws;
    const size_t MB = 1u << 20;
    ushort_t* WqT  = (ushort_t*)(ws + 0 * MB);
    ushort_t* WkT  = (ushort_t*)(ws + 2 * MB);
    ushort_t* WvT  = (ushort_t*)(ws + 4 * MB);
    ushort_t* WfcT = (ushort_t*)(ws + 6 * MB);
    ushort_t* qb   = (ushort_t*)(ws + 8 * MB);
    ushort_t* kb   = (ushort_t*)(ws + 16 * MB);
    ushort_t* vb   = (ushort_t*)(ws + 24 * MB);
    ushort_t* Qh   = (ushort_t*)(ws + 32 * MB);
    ushort_t* Kh   = (ushort_t*)(ws + 40 * MB);
    ushort_t* Vt   = (ushort_t*)(ws + 48 * MB);
    ushort_t* Oh   = (ushort_t*)(ws + 8 * MB);  // reuse qb slot after QKV GEMM

    const int M = M_TOK, D = D_MODEL;
    prep_fused<<<dim3(64, 32, 7), 256, 0, stream>>>(
        Wq, Wk, Wv, Wfc, WqT, WkT, WvT, WfcT, q, k, v, qb, kb, vb);

    // m-dim on blockIdx.x: same-A blocks land on the same XCD (id stride 32)
    gemm_qkv<<<dim3(M / 128, D / 128, 3), 256, 0, stream>>>(qb, kb, vb, WqT, WkT, WvT, Qh, Kh, Vt);

    attn64<<<dim3(N_HEAD, BATCH, SEQ / 64), 256, 0, stream>>>(Qh, Kh, Vt, Oh);

    gemm_fc<<<dim3(M / 128, D / 64), 256, 0, stream>>>(Oh, WfcT, out, bfc, q);

    ln_kernel<<<M, 256, 0, stream>>>(out, gamma, beta);
}

// Round 14
// 230.442 us; speedup vs baseline: 1.0114x; 1.0114x over previous
//
#include <hip/hip_runtime.h>

typedef float f32x4 __attribute__((ext_vector_type(4)));
typedef short short8 __attribute__((ext_vector_type(8)));
typedef short short4v __attribute__((ext_vector_type(4)));
typedef unsigned int uint2v __attribute__((ext_vector_type(2)));
typedef unsigned short ushort_t;

#define D_MODEL 1024
#define N_HEAD 16
#define SEQ 2048
#define BATCH 2
#define M_TOK 4096  // B*S
#define HD 1024     // N_HEAD*D_K
#define NT 32       // SEQ/64 k-tiles
#define APANEL 131072  // 4096*32 elements per A-side k-panel
#define WPANEL 32768   // 1024*32 elements per weight k-panel
// (1/sqrt(64)) * log2(e), folded into Q-GEMM epilogue; attention uses exp2
#define QSCALE_L2E 0.1803368801111f

__device__ __forceinline__ ushort_t f2bf(float f) {
    union { float f; unsigned int u; } x; x.f = f;
    unsigned int r = x.u + 0x7fffu + ((x.u >> 16) & 1u);
    return (ushort_t)(r >> 16);
}

__device__ __forceinline__ void async_copy16(const ushort_t* gptr, ushort_t* lptr) {
    __builtin_amdgcn_global_load_lds(
        (const __attribute__((address_space(1))) unsigned int*)gptr,
        (__attribute__((address_space(3))) unsigned int*)lptr, 16, 0, 0);
}

// ---- fused prep: z<4 weight transpose+cast -> panel layout [k/32][1024][32];
//      z>=4 q/k/v cast -> panel layout [k/32][4096][32] ----
// (round-7 lesson: in-GEMM fp32 consumption costs more than this pass saves)
__global__ __launch_bounds__(256) void prep_fused(const float* __restrict__ w0,
                                                  const float* __restrict__ w1,
                                                  const float* __restrict__ w2,
                                                  const float* __restrict__ w3,
                                                  ushort_t* __restrict__ o0,
                                                  ushort_t* __restrict__ o1,
                                                  ushort_t* __restrict__ o2,
                                                  ushort_t* __restrict__ o3,
                                                  const float* __restrict__ q,
                                                  const float* __restrict__ k,
                                                  const float* __restrict__ v,
                                                  ushort_t* __restrict__ qo,
                                                  ushort_t* __restrict__ ko,
                                                  ushort_t* __restrict__ vo) {
    const int z = blockIdx.z;
    const int tid = threadIdx.x;
    const int flat = blockIdx.x + 64 * blockIdx.y;  // 0..2047
    if (z < 4) {
        if (flat >= 1024) return;
        const int C = D_MODEL;
        const float* in = (z == 0) ? w0 : (z == 1) ? w1 : (z == 2) ? w2 : w3;
        ushort_t* out = (z == 0) ? o0 : (z == 1) ? o1 : (z == 2) ? o2 : o3;
        __shared__ ushort_t t[32][33];
        int bc = (flat & 31) * 32, br = (flat >> 5) * 32;  // br = k-block, bc = n-block
        int tx = tid & 31, ty = tid >> 5;
        for (int i = ty; i < 32; i += 8)
            t[i][tx] = f2bf(in[(size_t)(br + i) * C + bc + tx]);
        __syncthreads();
        // element (n = bc+i, k = br+tx) -> panel (br>>5), addr n*32 + tx
        size_t pbase = (size_t)(br >> 5) * WPANEL;
        for (int i = ty; i < 32; i += 8)
            out[pbase + (size_t)(bc + i) * 32 + tx] = t[tx][i];
    } else {
        const float* s = (z == 4) ? q : (z == 5) ? k : v;
        ushort_t* d = (z == 4) ? qo : (z == 5) ? ko : vo;
        size_t i = ((size_t)flat * 256 + tid) * 8;
        int m = (int)(i >> 10), k0 = (int)(i & 1023);
        float4 a = *(const float4*)(s + i);
        float4 b = *(const float4*)(s + i + 4);
        ushort_t tmp[8] = {f2bf(a.x), f2bf(a.y), f2bf(a.z), f2bf(a.w),
                           f2bf(b.x), f2bf(b.y), f2bf(b.z), f2bf(b.w)};
        *(short8*)(d + (size_t)(k0 >> 5) * APANEL + (size_t)m * 32 + (k0 & 31)) = *(short8*)tmp;
    }
}

// ---- QKV projection: 128x128 tile, BK=64 (2 panels/iter), grid.z batched ----
// ROUND-6 VERIFIED FORM (BK=32 dbuf regressed +3us in round 8 -> reverted).
// Grid (m, n, z): m on blockIdx.x so same-A blocks share an XCD L2.
// z==0: Q scaled by QSCALE_L2E. z==1: K. z==2: V -> blocked V4 layout.
__global__ __launch_bounds__(256) void gemm_qkv(const ushort_t* __restrict__ qb,
                                                const ushort_t* __restrict__ kb,
                                                const ushort_t* __restrict__ vb,
                                                const ushort_t* __restrict__ wq,
                                                const ushort_t* __restrict__ wk,
                                                const ushort_t* __restrict__ wv,
                                                ushort_t* __restrict__ Qo,
                                                ushort_t* __restrict__ Ko,
                                                ushort_t* __restrict__ V4) {
    __shared__ ushort_t As[2][128 * 32];
    __shared__ ushort_t Bs[2][128 * 32];
    const int z = blockIdx.z;
    const ushort_t* A = (z == 0) ? qb : (z == 1) ? kb : vb;
    const ushort_t* Bt = (z == 0) ? wq : (z == 1) ? wk : wv;
    const int tid = threadIdx.x;
    const int wave = tid >> 6, lane = tid & 63;
    const int quad = lane >> 4, l16 = lane & 15;
    const int m0 = blockIdx.x * 128, n0 = blockIdx.y * 128;
    const int wm = (wave >> 1) * 64, wn = (wave & 1) * 64;
    const int N = D_MODEL;

    f32x4 acc[4][4];
    for (int i = 0; i < 4; ++i)
        for (int j = 0; j < 4; ++j) acc[i][j] = (f32x4){0.f, 0.f, 0.f, 0.f};

    for (int it = 0; it < 16; ++it) {
        __syncthreads();
        const ushort_t* Ap = A + (size_t)(it * 2) * APANEL + (size_t)m0 * 32;
        const ushort_t* Bp = Bt + (size_t)(it * 2) * WPANEL + (size_t)n0 * 32;
        #pragma unroll
        for (int hf = 0; hf < 2; ++hf) {
            #pragma unroll
            for (int c = 0; c < 2; ++c) {
                int off = (wave * 2 + c) * 512;
                async_copy16(Ap + hf * APANEL + off + lane * 8, &As[hf][off] + lane * 8);
                async_copy16(Bp + hf * WPANEL + off + lane * 8, &Bs[hf][off] + lane * 8);
            }
        }
        __syncthreads();
        short8 af[4][2], bfr[4][2];
        #pragma unroll
        for (int i = 0; i < 4; ++i)
            #pragma unroll
            for (int sk = 0; sk < 2; ++sk)
                af[i][sk] = *(const short8*)&As[sk][(wm + i * 16 + l16) * 32 + quad * 8];
        #pragma unroll
        for (int j = 0; j < 4; ++j)
            #pragma unroll
            for (int sk = 0; sk < 2; ++sk)
                bfr[j][sk] = *(const short8*)&Bs[sk][(wn + j * 16 + l16) * 32 + quad * 8];
        #pragma unroll
        for (int sk = 0; sk < 2; ++sk)
            #pragma unroll
            for (int i = 0; i < 4; ++i)
                #pragma unroll
                for (int j = 0; j < 4; ++j)
                    acc[i][j] = __builtin_amdgcn_mfma_f32_16x16x32_bf16(af[i][sk], bfr[j][sk], acc[i][j], 0, 0, 0);
    }
    if (z == 2) {
        // V4 blocked layout: tile64 = 64-token group; w-subtile = i; token slot rotated
        const int tile64 = m0 + wm;
        const int b2 = tile64 >> 11;            // /SEQ
        const int kt = (tile64 & 2047) >> 6;
        #pragma unroll
        for (int i = 0; i < 4; ++i)
            #pragma unroll
            for (int j = 0; j < 4; ++j) {
                int n = n0 + wn + j * 16 + l16;
                int h2 = n >> 6, d = n & 63;
                int quadR = (quad + ((n >> 2) & 3)) & 3;
                ushort_t tmp[4];
                #pragma unroll
                for (int r = 0; r < 4; ++r) tmp[r] = f2bf(acc[i][j][r]);
                size_t dst = ((((size_t)(h2 * 2 + b2) * NT + kt) * 4 + i) << 10) + d * 16 + quadR * 4;
                *(short4v*)&V4[dst] = *(short4v*)tmp;
            }
    } else {
        ushort_t* C = (z == 0) ? Qo : Ko;
        const float scale = (z == 0) ? QSCALE_L2E : 1.0f;
        #pragma unroll
        for (int i = 0; i < 4; ++i)
            #pragma unroll
            for (int j = 0; j < 4; ++j) {
                int n = n0 + wn + j * 16 + l16;
                #pragma unroll
                for (int r = 0; r < 4; ++r) {
                    int m = m0 + wm + i * 16 + quad * 4 + r;
                    C[(size_t)m * N + n] = f2bf(acc[i][j][r] * scale);
                }
            }
    }
}

// ---- FC projection: 128x64 tiles, BK=64 panels, fused bias + residual, fp32 out ----
// ROUND-6 VERIFIED FORM. Grid (m, n): m on blockIdx.x for XCD L2 locality.
__global__ __launch_bounds__(256) void gemm_fc(const ushort_t* __restrict__ A,
                                               const ushort_t* __restrict__ Bt,
                                               float* __restrict__ Cf,
                                               const float* __restrict__ bias,
                                               const float* __restrict__ resid) {
    __shared__ ushort_t As[2][128 * 32];
    __shared__ ushort_t Bs[2][64 * 32];
    const int tid = threadIdx.x;
    const int wave = tid >> 6, lane = tid & 63;
    const int quad = lane >> 4, l16 = lane & 15;
    const int m0 = blockIdx.x * 128, n0 = blockIdx.y * 64;
    const int N = D_MODEL;

    f32x4 acc[2][4];
    for (int i = 0; i < 2; ++i)
        for (int j = 0; j < 4; ++j) acc[i][j] = (f32x4){0.f, 0.f, 0.f, 0.f};

    for (int it = 0; it < 16; ++it) {
        __syncthreads();
        const ushort_t* Ap = A + (size_t)(it * 2) * APANEL + (size_t)m0 * 32;
        const ushort_t* Bp = Bt + (size_t)(it * 2) * WPANEL + (size_t)n0 * 32;
        #pragma unroll
        for (int c = 0; c < 4; ++c) {  // A: 16 instrs, wave does 4
            int g = wave * 4 + c;
            int sk = g >> 3, off = (g & 7) * 512;
            async_copy16(Ap + sk * APANEL + off + lane * 8, &As[sk][off] + lane * 8);
        }
        #pragma unroll
        for (int c = 0; c < 2; ++c) {  // B: 8 instrs, wave does 2
            int g = wave * 2 + c;
            int sk = g >> 2, off = (g & 3) * 512;
            async_copy16(Bp + sk * WPANEL + off + lane * 8, &Bs[sk][off] + lane * 8);
        }
        __syncthreads();
        short8 af[2][2], bfr[4][2];
        #pragma unroll
        for (int i = 0; i < 2; ++i)
            #pragma unroll
            for (int sk = 0; sk < 2; ++sk)
                af[i][sk] = *(const short8*)&As[sk][(wave * 32 + i * 16 + l16) * 32 + quad * 8];
        #pragma unroll
        for (int j = 0; j < 4; ++j)
            #pragma unroll
            for (int sk = 0; sk < 2; ++sk)
                bfr[j][sk] = *(const short8*)&Bs[sk][(j * 16 + l16) * 32 + quad * 8];
        #pragma unroll
        for (int sk = 0; sk < 2; ++sk)
            #pragma unroll
            for (int i = 0; i < 2; ++i)
                #pragma unroll
                for (int j = 0; j < 4; ++j)
                    acc[i][j] = __builtin_amdgcn_mfma_f32_16x16x32_bf16(af[i][sk], bfr[j][sk], acc[i][j], 0, 0, 0);
    }
    #pragma unroll
    for (int i = 0; i < 2; ++i)
        #pragma unroll
        for (int j = 0; j < 4; ++j) {
            int n = n0 + j * 16 + l16;
            #pragma unroll
            for (int r = 0; r < 4; ++r) {
                int m = m0 + wave * 32 + i * 16 + quad * 4 + r;
                Cf[(size_t)m * N + n] = acc[i][j][r] + bias[n] + resid[(size_t)m * N + n];
            }
        }
}

// ---- flash attention: parity-unrolled (x2) K/V pipeline ----
// SESSION-FINAL VERIFIED KERNEL (55.7-56.5us, MfmaUtil 35%). Ledger:
//  - VALU trim (cvt_pk): counters moved, time flat -> latency-bound, not issue-bound.
//  - k-split x2 (cross-block combine): NaN twice -> abandoned.
//  - q-split x2: occupancy 21->49% but 112us -> occupancy NOT binding.
//  - parity kfA/kfB (no end-of-iter copy): removed forced per-iter vmcnt drain,
//    67->55.7us. K/V flight window >= 1.5 iterations.
//  - carried-PV: spilled (WRITE 9.2->22.4MB), 77.5us -> reverted (rule #20/T15).
//  - setprio T5: +2us regression (symmetric ~35/35 pipe pressure) -> reverted.
// Remaining headroom requires full structural rewrite (8-warp 32x32 + XOR-swz
// LDS, per Appendix B ladder) -- out of incremental-change risk budget.
__global__ __launch_bounds__(256, 3) void attn64(const ushort_t* __restrict__ Qh,
                                                 const ushort_t* __restrict__ Kh,
                                                 const ushort_t* __restrict__ V4,
                                                 ushort_t* __restrict__ O) {
    // loop: V buffers 4 waves x 3 bufs x 2KB = 24576 B; epilogue overlay 64x66 fp32 + lsb
    __shared__ __align__(16) char smem[25600];
    const int tid = threadIdx.x;
    const int wave = tid >> 6, lane = tid & 63;
    const int quad = lane >> 4, l16 = lane & 15;
    const int h = blockIdx.x, b = blockIdx.y, qt = blockIdx.z;
    const size_t base = (size_t)b * SEQ * HD + h * 64;
    const ushort_t* Qb = Qh + base + (size_t)(qt * 64) * HD;
    const ushort_t* Kb = Kh + base;
    // wave's V stream: V4[h][b][kt][wave][1024], kt stride 4096 el
    const ushort_t* Vg = V4 + (((size_t)(h * 2 + b) * NT * 4) + wave) * 1024 + lane * 8;

    ushort_t* Vw = (ushort_t*)smem + wave * 3072;
    float* lsb = (float*)(smem + 24576);

    short8 qf[4][2];
    #pragma unroll
    for (int nt = 0; nt < 4; ++nt)
        #pragma unroll
        for (int s = 0; s < 2; ++s)
            qf[nt][s] = *(const short8*)(Qb + (size_t)(nt * 16 + l16) * HD + s * 32 + quad * 8);

    f32x4 oacc[4][4];
    #pragma unroll
    for (int nt = 0; nt < 4; ++nt)
        #pragma unroll
        for (int dt = 0; dt < 4; ++dt) oacc[nt][dt] = (f32x4){0.f, 0.f, 0.f, 0.f};
    float lsum[4] = {0.f, 0.f, 0.f, 0.f};

    const ushort_t* Kr = Kb + (size_t)(wave * 16 + l16) * HD + quad * 8;
    ushort_t* VLd = Vw + lane * 8;

    // prologue issue order: qf(8) [above], K0->kfA(2), V0(2), K1->kfB(2), V1(2)
    short8 kfA[2], kfB[2];
    #pragma unroll
    for (int s = 0; s < 2; ++s) kfA[s] = *(const short8*)(Kr + s * 32);
    #pragma unroll
    for (int c = 0; c < 2; ++c) async_copy16(Vg + c * 512, VLd + c * 512);
    #pragma unroll
    for (int s = 0; s < 2; ++s) kfB[s] = *(const short8*)(Kr + (size_t)64 * HD + s * 32);
    #pragma unroll
    for (int c = 0; c < 2; ++c) async_copy16(Vg + 4096 + c * 512, VLd + 1024 + c * 512);

    ushort_t *s0 = Vw, *s1 = Vw + 1024, *s2 = Vw + 2048;
    const int rot = (l16 >> 2) & 3;

// one kt step. KF = kfA/kfB by parity (no copies). After the S-MFMAs consume
// KF, reload it with K(KT+2) (WAR-clean) and issue V(KT+2) DMA into SPF.
#define ATTN_STEP(KT, KF, SUSE, SPF, WAITIMM, DO_PF)                                         \
    {                                                                                        \
        __builtin_amdgcn_s_waitcnt(WAITIMM);                                                 \
        short4v vf[4];                                                                       \
        _Pragma("unroll")                                                                    \
        for (int dt = 0; dt < 4; ++dt)                                                       \
            vf[dt] = *(const short4v*)&(SUSE)[(dt * 16 + l16) * 16 + (((quad + rot) & 3) * 4)]; \
        f32x4 sacc[4];                                                                       \
        _Pragma("unroll")                                                                    \
        for (int nt = 0; nt < 4; ++nt) sacc[nt] = (f32x4){0.f, 0.f, 0.f, 0.f};               \
        _Pragma("unroll")                                                                    \
        for (int s = 0; s < 2; ++s)                                                          \
            _Pragma("unroll")                                                                \
            for (int nt = 0; nt < 4; ++nt)                                                   \
                sacc[nt] = __builtin_amdgcn_mfma_f32_16x16x32_bf16(KF[s], qf[nt][s],         \
                                                                   sacc[nt], 0, 0, 0);       \
        if (DO_PF) {                                                                         \
            _Pragma("unroll")                                                                \
            for (int s = 0; s < 2; ++s)                                                      \
                KF[s] = *(const short8*)(Kr + (size_t)((KT) + 2) * 64 * HD + s * 32);        \
            _Pragma("unroll")                                                                \
            for (int c = 0; c < 2; ++c)                                                      \
                async_copy16(Vg + (size_t)((KT) + 2) * 4096 + c * 512,                       \
                             (SPF) + lane * 8 + c * 512);                                    \
        }                                                                                    \
        short4v pf[4];                                                                       \
        _Pragma("unroll")                                                                    \
        for (int nt = 0; nt < 4; ++nt) {                                                     \
            float p0 = __builtin_amdgcn_exp2f(sacc[nt][0]);                                  \
            float p1 = __builtin_amdgcn_exp2f(sacc[nt][1]);                                  \
            float p2 = __builtin_amdgcn_exp2f(sacc[nt][2]);                                  \
            float p3 = __builtin_amdgcn_exp2f(sacc[nt][3]);                                  \
            lsum[nt] += (p0 + p1) + (p2 + p3);                                               \
            unsigned int lo, hi;                                                             \
            asm("v_cvt_pk_bf16_f32 %0, %1, %2" : "=v"(lo) : "v"(p0), "v"(p1));               \
            asm("v_cvt_pk_bf16_f32 %0, %1, %2" : "=v"(hi) : "v"(p2), "v"(p3));               \
            uint2v pk;                                                                       \
            pk.x = lo;                                                                       \
            pk.y = hi;                                                                       \
            pf[nt] = __builtin_bit_cast(short4v, pk);                                        \
        }                                                                                    \
        _Pragma("unroll")                                                                    \
        for (int nt = 0; nt < 4; ++nt)                                                       \
            _Pragma("unroll")                                                                \
            for (int dt = 0; dt < 4; ++dt)                                                   \
                oacc[nt][dt] = __builtin_amdgcn_mfma_f32_16x16x16bf16_1k(pf[nt], vf[dt],     \
                                                                         oacc[nt][dt],       \
                                                                         0, 0, 0);           \
    }

    for (int kt0 = 0; kt0 < 30; kt0 += 2) {
        ATTN_STEP(kt0,     kfA, s0, s2, 0x0F74, true);   // vmcnt(4)
        ATTN_STEP(kt0 + 1, kfB, s1, s0, 0x0F74, true);   // vmcnt(4)
        // ring rotate by 2: next body's (s0,s1,s2) = (old s2, old s0, old s1)
        ushort_t* t = s0; s0 = s2; s2 = s1; s1 = t;
    }
    ATTN_STEP(30, kfA, s0, s2, 0x0F74, false);           // vmcnt(4)
    ATTN_STEP(31, kfB, s1, s0, 0x0F70, false);           // vmcnt(0)
#undef ATTN_STEP

    #pragma unroll
    for (int nt = 0; nt < 4; ++nt) {
        lsum[nt] += __shfl_xor(lsum[nt], 16, 64);
        lsum[nt] += __shfl_xor(lsum[nt], 32, 64);
    }
    if (quad == 0) {
        #pragma unroll
        for (int nt = 0; nt < 4; ++nt) lsb[wave * 64 + nt * 16 + l16] = lsum[nt];
    }
    __syncthreads();

    float* R = (float*)smem;  // 64x66 fp32
    #pragma unroll
    for (int w = 0; w < 4; ++w) {
        if (wave == w) {
            #pragma unroll
            for (int nt = 0; nt < 4; ++nt)
                #pragma unroll
                for (int dt = 0; dt < 4; ++dt)
                    #pragma unroll
                    for (int i = 0; i < 4; ++i) {
                        int idx = (nt * 16 + quad * 4 + i) * 66 + dt * 16 + l16;
                        if (w == 0) R[idx] = oacc[nt][dt][i];
                        else        R[idx] += oacc[nt][dt][i];
                    }
        }
        __syncthreads();
    }
    float inv[4];
    #pragma unroll
    for (int i = 0; i < 4; ++i) {
        int qrow = wave * 16 + quad * 4 + i;
        float t = lsb[qrow] + lsb[64 + qrow] + lsb[128 + qrow] + lsb[192 + qrow];
        inv[i] = 1.f / t;
    }
    // O in panel layout: k = h*64 + dt*16 + l16 -> panel h*2 + (dt>>1)
    #pragma unroll
    for (int i = 0; i < 4; ++i) {
        int qrow = wave * 16 + quad * 4 + i;
        size_t tok = (size_t)b * SEQ + qt * 64 + qrow;
        #pragma unroll
        for (int dt = 0; dt < 4; ++dt) {
            int d = dt * 16 + l16;
            size_t dst = (size_t)(h * 2 + (dt >> 1)) * APANEL + tok * 32 + (dt & 1) * 16 + l16;
            O[dst] = f2bf(R[qrow * 66 + d] * inv[i]);
        }
    }
}

// ---------------- in-place LayerNorm, one block per row ----------------
__global__ __launch_bounds__(256) void ln_kernel(float* __restrict__ x,
                                                 const float* __restrict__ gamma,
                                                 const float* __restrict__ beta) {
    const int D = D_MODEL;
    float* xr = x + (size_t)blockIdx.x * D;
    const int tid = threadIdx.x;
    float4 v = *(const float4*)(xr + tid * 4);
    float s = v.x + v.y + v.z + v.w;
    float s2 = v.x * v.x + v.y * v.y + v.z * v.z + v.w * v.w;
    #pragma unroll
    for (int off = 1; off < 64; off <<= 1) {
        s += __shfl_xor(s, off, 64);
        s2 += __shfl_xor(s2, off, 64);
    }
    __shared__ float ws1[4], ws2[4];
    int wave = tid >> 6, lane = tid & 63;
    if (lane == 0) { ws1[wave] = s; ws2[wave] = s2; }
    __syncthreads();
    s = ws1[0] + ws1[1] + ws1[2] + ws1[3];
    s2 = ws2[0] + ws2[1] + ws2[2] + ws2[3];
    float mean = s * (1.f / D);
    float var = s2 * (1.f / D) - mean * mean;
    float rstd = rsqrtf(var + 1e-6f);
    float4 g = *(const float4*)(gamma + tid * 4);
    float4 bt = *(const float4*)(beta + tid * 4);
    float4 o;
    o.x = (v.x - mean) * rstd * g.x + bt.x;
    o.y = (v.y - mean) * rstd * g.y + bt.y;
    o.z = (v.z - mean) * rstd * g.z + bt.z;
    o.w = (v.w - mean) * rstd * g.w + bt.w;
    *(float4*)(xr + tid * 4) = o;
}

extern "C" void kernel_launch(void* const* d_in, const int* in_sizes, int n_in,
                              void* d_out, int out_size, void* d_ws, size_t ws_size,
                              hipStream_t stream) {
    const float* q = (const float*)d_in[0];
    const float* k = (const float*)d_in[1];
    const float* v = (const float*)d_in[2];
    const float* Wq = (const float*)d_in[3];
    const float* Wk = (const float*)d_in[4];
    const float* Wv = (const float*)d_in[5];
    const float* Wfc = (const float*)d_in[6];
    const float* bfc = (const float*)d_in[7];
    const float* gamma = (const float*)d_in[8];
    const float* beta = (const float*)d_in[9];
    float* out = (float*)d_out;

    char* ws = (char*)d_ws;
    const size_t MB = 1u << 20;
    ushort_t* WqT  = (ushort_t*)(ws + 0 * MB);
    ushort_t* WkT  = (ushort_t*)(ws + 2 * MB);
    ushort_t* WvT  = (ushort_t*)(ws + 4 * MB);
    ushort_t* WfcT = (ushort_t*)(ws + 6 * MB);
    ushort_t* qb   = (ushort_t*)(ws + 8 * MB);
    ushort_t* kb   = (ushort_t*)(ws + 16 * MB);
    ushort_t* vb   = (ushort_t*)(ws + 24 * MB);
    ushort_t* Qh   = (ushort_t*)(ws + 32 * MB);
    ushort_t* Kh   = (ushort_t*)(ws + 40 * MB);
    ushort_t* Vt   = (ushort_t*)(ws + 48 * MB);
    ushort_t* Oh   = (ushort_t*)(ws + 8 * MB);  // reuse qb slot after QKV GEMM

    const int M = M_TOK, D = D_MODEL;
    prep_fused<<<dim3(64, 32, 7), 256, 0, stream>>>(
        Wq, Wk, Wv, Wfc, WqT, WkT, WvT, WfcT, q, k, v, qb, kb, vb);

    // m-dim on blockIdx.x: same-A blocks land on the same XCD (id stride 32)
    gemm_qkv<<<dim3(M / 128, D / 128, 3), 256, 0, stream>>>(qb, kb, vb, WqT, WkT, WvT, Qh, Kh, Vt);

    attn64<<<dim3(N_HEAD, BATCH, SEQ / 64), 256, 0, stream>>>(Qh, Kh, Vt, Oh);

    gemm_fc<<<dim3(M / 128, D / 64), 256, 0, stream>>>(Oh, WfcT, out, bfc, q);

    ln_kernel<<<M, 256, 0, stream>>>(out, gamma, beta);
}